// Round 6
// baseline (16.418 us; speedup 1.0000x reference)
//
#include <hip/hip_runtime.h>
#include <math.h>

#define B_SZ 256
#define U_SZ 4096
#define V_SZ 80
#define H_SZ 1024
#define K_SZ 10
#define CPRE 64   // pt[CPRE..U] is bulk-zero-filled pre-A

// d_out layout (floats, concatenated in return order):
//   [0, B*V)                       w            (256*80   = 20480)
//   [B*V, B*V + B*K)               new_kappa    (256*10   = 2560)
//   [B*V + B*K, ... + B*(U+1))     phi_term     (256*4097 = 1048832)
#define OUT_W_OFF      0
#define OUT_NK_OFF     (B_SZ * V_SZ)
#define OUT_PT_OFF     (B_SZ * V_SZ + B_SZ * K_SZ)

// One block (1024 threads = 16 waves) per batch. TWO barriers total.
//   entry:  warm c rows [0,~102) into L2 (loads kept live via asm sink),
//           x -> registers, bulk zero-fill pt[CPRE..U]
//   pre-A:  lin = x @ W.T (16 waves, float4)
//   A ----  (single drain of all entry HBM traffic)
//   all threads: redundant scalars a/beta/nk + analytic cutoff from lin_s
//                (block-uniform; terms beyond cutoff are < e^-60)
//   waves 0-14: w[b,v] = sum_u phi(u)*c[u,v], phi recomputed inline,
//               c read direct from global (L2-warm)
//   wave 15:    pt[0..ucut] exp-compute, zero gap (ucut,CPRE), new_kappa
//   E ----  (LDS-only partial reduce)
//   threads 0-79: reduce 12 partials, store w
__global__ __launch_bounds__(1024) void fused_softwindow(
        const float* __restrict__ x,
        const float* __restrict__ c,
        const float* __restrict__ kappa,
        const float* __restrict__ W,
        const float* __restrict__ bias,
        const int*   __restrict__ lens,
        float* __restrict__ out) {
    __shared__ float lin_s[32];
    __shared__ float wpart[12][V_SZ];

    const int b    = blockIdx.x;
    const int tid  = threadIdx.x;
    const int wave = tid >> 6;
    const int lane = tid & 63;
    const int len  = lens[b];

    const float*  cb  = c + (size_t)b * U_SZ * V_SZ;
    const float4* cb4 = (const float4*)cb;

    // entry: warm c rows [0, 102) into L1/L2 (2048 float4 = 32 KB)
    float4 cw0 = cb4[tid];
    float4 cw1 = cb4[tid + 1024];

    // entry: x -> registers (per-lane slice, reused across k rows)
    const float4* xb4 = (const float4*)(x + (size_t)b * H_SZ);
    float4 xv[4];
    #pragma unroll
    for (int j = 0; j < 4; ++j) xv[j] = xb4[lane + 64 * j];

    // entry: bulk zero-fill pt[CPRE..U] (drains at A, before any rewrite)
    float* pt = out + OUT_PT_OFF + (size_t)b * (U_SZ + 1);
    #pragma unroll
    for (int j = 0; j < 4; ++j) {
        int u = CPRE + tid + 1024 * j;
        if (u <= U_SZ) pt[u] = 0.f;
    }

    // phase 1: lin = x @ W.T (waves 0..13 do 2 rows, 14..15 do 1)
    for (int k = wave; k < 3 * K_SZ; k += 16) {
        const float4* Wk4 = (const float4*)(W + (size_t)k * H_SZ);
        float p = 0.f;
        #pragma unroll
        for (int j = 0; j < 4; ++j) {
            float4 wv = Wk4[lane + 64 * j];
            p += wv.x * xv[j].x + wv.y * xv[j].y +
                 wv.z * xv[j].z + wv.w * xv[j].w;
        }
        #pragma unroll
        for (int off = 32; off > 0; off >>= 1) p += __shfl_down(p, off);
        if (lane == 0) lin_s[k] = p;
    }

    // keep the c-warm loads live (prevent DCE) — drained at A anyway
    asm volatile("" :: "v"(cw0.x), "v"(cw0.y), "v"(cw0.z), "v"(cw0.w),
                       "v"(cw1.x), "v"(cw1.y), "v"(cw1.z), "v"(cw1.w));

    __syncthreads();  // A: lin_s ready; all entry vmem drained

    // all threads: block-uniform scalars + cutoff (30 expf, SIMD-redundant)
    float a_[K_SZ], nb_[K_SZ], nk_[K_SZ];
    float cut = 0.f;
    #pragma unroll
    for (int k = 0; k < K_SZ; ++k) {
        float ah = lin_s[k]             + bias[k];
        float bh = lin_s[K_SZ + k]      + bias[K_SZ + k];
        float kh = lin_s[2 * K_SZ + k]  + bias[2 * K_SZ + k];
        float al = expf(ah);
        float bt = expf(bh);
        float nkv = kappa[b * K_SZ + k] + expf(kh - 3.9f);
        a_[k]  = al;
        nb_[k] = -bt;
        nk_[k] = nkv;
        // term_k(u) = exp(ah - bt*(nk-u)^2) < e^-60 beyond this u:
        cut = fmaxf(cut, nkv + sqrtf((60.f + fmaxf(ah, 0.f)) / bt));
    }
    int ucut = (int)cut + 1;
    if (ucut > U_SZ) ucut = U_SZ;

    if (tid < 12 * V_SZ) {
        // waves 0-14: w accumulation, phi inline, c direct from global
        const int v = tid % V_SZ;
        const int r = tid / V_SZ;
        const int ulim = min(len, ucut + 1);
        float acc = 0.f;
        for (int u = r; u < ulim; u += 12) {
            const float fu = (float)u;
            float s = 0.f;
            #pragma unroll
            for (int k = 0; k < K_SZ; ++k) {
                float d = nk_[k] - fu;
                s += a_[k] * expf(nb_[k] * d * d);
            }
            acc += s * cb[(size_t)u * V_SZ + v];
        }
        wpart[r][v] = acc;
    } else {
        // wave 15: phi_termination head + gap zero + new_kappa
        const int t = tid - 12 * V_SZ;  // 0..63
        for (int u = t; u <= ucut; u += 64) {
            const float fu = (float)u;
            float s = 0.f;
            #pragma unroll
            for (int k = 0; k < K_SZ; ++k) {
                float d = nk_[k] - fu;
                s += a_[k] * expf(nb_[k] * d * d);
            }
            pt[u] = s;
        }
        for (int u = ucut + 1 + t; u < CPRE; u += 64) pt[u] = 0.f;
        if (t < K_SZ) {
            // recompute via memory-indexed loads (no dynamic VGPR indexing)
            float kh = lin_s[2 * K_SZ + t] + bias[2 * K_SZ + t];
            out[OUT_NK_OFF + b * K_SZ + t] =
                kappa[b * K_SZ + t] + expf(kh - 3.9f);
        }
    }

    __syncthreads();  // E: wpart ready (LDS-only dependency)

    if (tid < V_SZ) {
        float s = 0.f;
        #pragma unroll
        for (int r = 0; r < 12; ++r) s += wpart[r][tid];
        out[OUT_W_OFF + b * V_SZ + tid] = s;
    }
}

extern "C" void kernel_launch(void* const* d_in, const int* in_sizes, int n_in,
                              void* d_out, int out_size, void* d_ws, size_t ws_size,
                              hipStream_t stream) {
    const float* x     = (const float*)d_in[0];
    const float* c     = (const float*)d_in[1];
    const float* kappa = (const float*)d_in[2];
    const float* W     = (const float*)d_in[3];
    const float* bias  = (const float*)d_in[4];
    const int*   lens  = (const int*)d_in[5];
    float* out = (float*)d_out;

    fused_softwindow<<<B_SZ, 1024, 0, stream>>>(x, c, kappa, W, bias, lens, out);
}

// Round 7
// 10.746 us; speedup vs baseline: 1.5278x; 1.5278x over previous
//
#include <hip/hip_runtime.h>
#include <math.h>

#define B_SZ 256
#define U_SZ 4096
#define V_SZ 80
#define H_SZ 1024
#define K_SZ 10
#define CPRE 64   // c rows held in registers then LDS per batch
#define CPRE_F4 (CPRE * V_SZ / 4)   // 1280 float4

// d_out layout (floats, concatenated in return order):
//   [0, B*V)                       w            (256*80   = 20480)
//   [B*V, B*V + B*K)               new_kappa    (256*10   = 2560)
//   [B*V + B*K, ... + B*(U+1))     phi_term     (256*4097 = 1048832)
#define OUT_W_OFF      0
#define OUT_NK_OFF     (B_SZ * V_SZ)
#define OUT_PT_OFF     (B_SZ * V_SZ + B_SZ * K_SZ)

// One block (1024 threads = 16 waves) per batch. Barrier chain A-B-D-E;
// the 4 MB phi_term zero-fill is DEFERRED to after the last barrier so no
// barrier ever drains it (it retires at kernel end, streaming full-BW).
//   entry:  c rows (64x80 = 1280 float4) -> registers, kappa/bias prefetch,
//           zero phi_s (LDS)
//   pre-A:  lin = x @ W.T (x direct from global, L1-cached)
//   A ----  (drain of entry loads; lin_s ready)
//   creg -> LDS ; wave-0 scalars + analytic cutoff (terms beyond < e^-60)
//   B ----
//   phase 3: exp-compute pt[0..ucut] + phi_s
//   D ----
//   phase 4: w partials from LDS c rows (+ rare global tail)
//   E ----  (LDS-only)
//   reduce+store w ; deferred zero-fill pt[(ucut,U]] (nontemporal)
__global__ __launch_bounds__(1024) void fused_softwindow(
        const float* __restrict__ x,
        const float* __restrict__ c,
        const float* __restrict__ kappa,
        const float* __restrict__ W,
        const float* __restrict__ bias,
        const int*   __restrict__ lens,
        float* __restrict__ out) {
    __shared__ float cs[CPRE * V_SZ];
    __shared__ float lin_s[32];
    __shared__ float a_s[K_SZ], nb_s[K_SZ], nk_s[K_SZ];
    __shared__ float phi_s[U_SZ];
    __shared__ float wpart[12][V_SZ];
    __shared__ int   ucut_sh;

    const int b    = blockIdx.x;
    const int tid  = threadIdx.x;
    const int wave = tid >> 6;
    const int lane = tid & 63;
    const int len  = lens[b];

    const float*  cb  = c + (size_t)b * U_SZ * V_SZ;
    const float4* cb4 = (const float4*)cb;

    // entry: c prefetch into registers — exactly CPRE_F4 = 1280 float4
    float4 creg0, creg1;
    creg0 = cb4[tid];                       // tid <  1024: always in range
    if (tid < CPRE_F4 - 1024) creg1 = cb4[tid + 1024];  // 256 threads

    // entry: kappa/bias prefetch (used by wave 0 in phase 2)
    float kap = 0.f, bs0 = 0.f, bs1 = 0.f, bs2 = 0.f;
    if (tid < K_SZ) {
        kap = kappa[b * K_SZ + tid];
        bs0 = bias[tid];
        bs1 = bias[K_SZ + tid];
        bs2 = bias[2 * K_SZ + tid];
    }

    // zero phi_s (same thread re-writes same indices in phase 3a)
    #pragma unroll
    for (int i = tid; i < U_SZ; i += 1024) phi_s[i] = 0.f;

    // phase 1: lin = x @ W.T, x and W direct from global
    {
        const float4* xb4 = (const float4*)(x + (size_t)b * H_SZ);
        float4 xv[4];
        #pragma unroll
        for (int j = 0; j < 4; ++j) xv[j] = xb4[lane + 64 * j];
        for (int k = wave; k < 3 * K_SZ; k += 16) {
            const float4* Wk4 = (const float4*)(W + (size_t)k * H_SZ);
            float p = 0.f;
            #pragma unroll
            for (int j = 0; j < 4; ++j) {
                float4 wv = Wk4[lane + 64 * j];
                p += wv.x * xv[j].x + wv.y * xv[j].y +
                     wv.z * xv[j].z + wv.w * xv[j].w;
            }
            #pragma unroll
            for (int off = 32; off > 0; off >>= 1) p += __shfl_down(p, off);
            if (lane == 0) lin_s[k] = p;
        }
    }

    __syncthreads();  // A: lin_s ready; entry loads drained

    // creg -> LDS layout bounce (visible to phase 4 after barrier D)
    {
        float4* cs4 = (float4*)cs;
        cs4[tid] = creg0;
        if (tid < CPRE_F4 - 1024) cs4[tid + 1024] = creg1;
    }

    // phase 2: per-k scalars + in-wave cutoff reduce (wave 0 only)
    if (wave == 0) {
        float cut = 0.f;
        if (lane < K_SZ) {
            const int k = lane;
            float ah = lin_s[k]            + bs0;
            float bh = lin_s[K_SZ + k]     + bs1;
            float kh = lin_s[2 * K_SZ + k] + bs2;
            float alpha = expf(ah);
            float beta  = expf(bh);
            float nk    = kap + expf(kh - 3.9f);
            a_s[k]  = alpha;
            nb_s[k] = -beta;
            nk_s[k] = nk;
            // term_k(u) = exp(ah - beta*(nk-u)^2) < e^-60 beyond this u:
            cut = nk + sqrtf((60.f + fmaxf(ah, 0.f)) / beta);
            out[OUT_NK_OFF + b * K_SZ + k] = nk;
        }
        #pragma unroll
        for (int off = 8; off > 0; off >>= 1)
            cut = fmaxf(cut, __shfl_xor(cut, off));
        if (lane == 0) {
            int uc = (int)cut + 1;
            ucut_sh = uc > U_SZ ? U_SZ : uc;
        }
    }
    __syncthreads();  // B: a_s/nb_s/nk_s/ucut_sh + cs ready

    const int ucut = ucut_sh;
    float* pt = out + OUT_PT_OFF + (size_t)b * (U_SZ + 1);

    // phase 3a: compute region u in [0, ucut] (typically one iteration)
    for (int u = tid; u <= ucut; u += 1024) {
        const float fu = (float)u;
        float s = 0.f;
        #pragma unroll
        for (int k = 0; k < K_SZ; ++k) {
            float d = nk_s[k] - fu;
            s += a_s[k] * expf(nb_s[k] * d * d);
        }
        pt[u] = s;
        if (u < len && u < U_SZ) phi_s[u] = s;
    }

    __syncthreads();  // D: phi_s ready

    // phase 4: w[b,v] (phi_s is exactly 0 beyond ulim)
    const int ulim = min(min(len, ucut + 1), U_SZ);
    if (tid < 12 * V_SZ) {
        const int v = tid % V_SZ;
        const int r = tid / V_SZ;
        float acc = 0.f;
        #pragma unroll
        for (int j = 0; j < 6; ++j) {
            const int u = r + 12 * j;
            if (u < CPRE) acc += phi_s[u] * cs[u * V_SZ + v];
        }
        if (ulim > CPRE) {  // rare tail: rows not prefetched
            int u0 = r + ((CPRE - r + 11) / 12) * 12;
            for (int u = u0; u < ulim; u += 12)
                acc += phi_s[u] * cb[(size_t)u * V_SZ + v];
        }
        wpart[r][v] = acc;
    }
    __syncthreads();  // E

    if (tid < V_SZ) {
        float s = 0.f;
        #pragma unroll
        for (int r = 0; r < 12; ++r) s += wpart[r][tid];
        out[OUT_W_OFF + b * V_SZ + tid] = s;
    }

    // deferred bulk zero-fill pt[(ucut, U]] — after the last barrier, so no
    // barrier drains these 4 MB of streaming stores; nontemporal to keep L2.
    #pragma unroll
    for (int j = 0; j < 4; ++j) {
        int u = ucut + 1 + tid + 1024 * j;
        if (u <= U_SZ) __builtin_nontemporal_store(0.f, &pt[u]);
    }
    {   // tail (U+1 - (ucut+1) can exceed 4096 only if ucut < 0; safe guard)
        int u = ucut + 1 + tid + 4096;
        if (u <= U_SZ) __builtin_nontemporal_store(0.f, &pt[u]);
    }
}

extern "C" void kernel_launch(void* const* d_in, const int* in_sizes, int n_in,
                              void* d_out, int out_size, void* d_ws, size_t ws_size,
                              hipStream_t stream) {
    const float* x     = (const float*)d_in[0];
    const float* c     = (const float*)d_in[1];
    const float* kappa = (const float*)d_in[2];
    const float* W     = (const float*)d_in[3];
    const float* bias  = (const float*)d_in[4];
    const int*   lens  = (const int*)d_in[5];
    float* out = (float*)d_out;

    fused_softwindow<<<B_SZ, 1024, 0, stream>>>(x, c, kappa, W, bias, lens, out);
}